// Round 7
// baseline (209.416 us; speedup 1.0000x reference)
//
#include <hip/hip_runtime.h>
#include <math.h>

#define DIMC 256
#define DST 16
#define DIN 512
#define BB 2
#define HH 48
#define WW 48
#define LL (HH*WW)      // 2304
#define MM (BB*LL)      // 4608
#define CH 12           // chunk length for the scan
#define NC 192          // number of chunks (CH*NC == LL)
#define NGRP (BB*DIN)   // 1024 (b,d) channels
#define NSEQ (NGRP*DST) // 16384 scalar recurrences
#define LTILE 16        // LN positions per block
#define NBLN (BB*(LL/LTILE))   // 288 LN blocks
#define W0N (1024*256)
#define W1N (48*512)
#define W2N (256*512)
#define NBW  ((W0N+W1N+W2N)/256)  // 1632 weight-convert blocks

typedef unsigned short ushort_t;
typedef __attribute__((ext_vector_type(8))) short bf16x8;
typedef __attribute__((ext_vector_type(4))) float f32x4;

__device__ __forceinline__ float silu_f(float a){ return a / (1.f + expf(-a)); }
__device__ __forceinline__ float softplus_f(float a){ return a > 20.f ? a : log1pf(__expf(a)); }
__device__ __forceinline__ ushort_t f2bf(float f) {
    unsigned u = __float_as_uint(f);
    u += 0x7FFFu + ((u >> 16) & 1u);
    return (ushort_t)(u >> 16);
}
__device__ __forceinline__ float bf2f(ushort_t h) {
    return __uint_as_float(((unsigned)h) << 16);
}

// ============ prep: LayerNorm (blocks 0..NBLN-1) + weight bf16 convert ============
__global__ __launch_bounds__(256) void prep_kernel(const float* __restrict__ x,
    const float* __restrict__ w, const float* __restrict__ bgain, ushort_t* __restrict__ xn,
    const float* __restrict__ w0, const float* __restrict__ w1, const float* __restrict__ w2,
    const float* __restrict__ A_log,
    ushort_t* __restrict__ o0, ushort_t* __restrict__ o1, ushort_t* __restrict__ o2,
    float* __restrict__ A2) {
    __shared__ float T2[LTILE][DIMC + 4];
    __shared__ float PS[16][17], PS2[16][17];
    __shared__ float MUB[LTILE], RB[LTILE];
    int blk = blockIdx.x;
    int t = threadIdx.x;
    if (blk >= NBLN) {
        int i = (blk - NBLN) * 256 + t;
        if (i < W0N) o0[i] = f2bf(w0[i]);
        else if (i < W0N + W1N) o1[i - W0N] = f2bf(w1[i - W0N]);
        else o2[i - W0N - W1N] = f2bf(w2[i - W0N - W1N]);
        if (i < DIN*DST) A2[i] = -__expf(A_log[i]);
        return;
    }
    int b = blk / (LL/LTILE);
    int l0 = (blk % (LL/LTILE)) * LTILE;
    int p = t & 15, g = t >> 4;
    float v[16];
    float s = 0.f, s2 = 0.f;
    #pragma unroll
    for (int cc = 0; cc < 16; cc++) {
        int c = g*16 + cc;
        float vv = x[((size_t)(b*DIMC + c))*LL + l0 + p];
        v[cc] = vv;
        s += vv; s2 += vv*vv;
    }
    PS[g][p] = s; PS2[g][p] = s2;
    __syncthreads();
    if (t < 16) {
        float tot = 0.f, tot2 = 0.f;
        #pragma unroll
        for (int gg = 0; gg < 16; gg++) { tot += PS[gg][t]; tot2 += PS2[gg][t]; }
        float mu = tot * (1.f/DIMC);
        float var = tot2 * (1.f/DIMC) - mu*mu;
        MUB[t] = mu;
        RB[t] = rsqrtf(var + 1e-5f);
    }
    __syncthreads();
    float mu = MUB[p], r = RB[p];
    #pragma unroll
    for (int cc = 0; cc < 16; cc++) {
        int c = g*16 + cc;
        T2[p][c] = (v[cc] - mu) * r * w[c] + bgain[c];
    }
    __syncthreads();
    int c4 = (t & 63) * 4;
    int prow = t >> 6;
    #pragma unroll
    for (int pp = 0; pp < 4; pp++) {
        int pos = pp*4 + prow;
        float4 q = *(const float4*)&T2[pos][c4];
        ushort4 o;
        o.x = f2bf(q.x); o.y = f2bf(q.y); o.z = f2bf(q.z); o.w = f2bf(q.w);
        *(ushort4*)&xn[((size_t)(b*LL + l0 + pos))*DIMC + c4] = o;
    }
}

// ------- 128x128 MFMA GEMM for in_proj, split epilogue: xs bf16 | z bf16 ---------
__global__ __launch_bounds__(256) void mfma_gemm128_split(const ushort_t* __restrict__ A,
    const ushort_t* __restrict__ W, ushort_t* __restrict__ Xs, ushort_t* __restrict__ Zb,
    int K) {   // M=MM, N=1024
    __shared__ ushort_t Asl[128][72];
    __shared__ ushort_t Bsl[128][72];
    int tid = threadIdx.x;
    int bm = blockIdx.y * 128;
    int bn = blockIdx.x * 128;
    int w = tid >> 6, l = tid & 63;
    int wr = (w >> 1) * 64, wc = (w & 1) * 64;
    int fr = l & 15, fg = l >> 4;
    f32x4 acc[4][4] = {};
    for (int k0 = 0; k0 < K; k0 += 64) {
        #pragma unroll
        for (int s = 0; s < 4; s++) {
            int c = tid + s*256;
            int r = c >> 3, c8 = (c & 7) * 8;
            *(uint4*)&Asl[r][c8] = *(const uint4*)(A + (size_t)(bm + r)*K + k0 + c8);
            *(uint4*)&Bsl[r][c8] = *(const uint4*)(W + (size_t)(bn + r)*K + k0 + c8);
        }
        __syncthreads();
        #pragma unroll
        for (int kk = 0; kk < 2; kk++) {
            int ko = kk*32 + fg*8;
            bf16x8 af[4], bfm[4];
            #pragma unroll
            for (int i = 0; i < 4; i++) af[i] = *(const bf16x8*)&Asl[wr + i*16 + fr][ko];
            #pragma unroll
            for (int j = 0; j < 4; j++) bfm[j] = *(const bf16x8*)&Bsl[wc + j*16 + fr][ko];
            #pragma unroll
            for (int i = 0; i < 4; i++)
                #pragma unroll
                for (int j = 0; j < 4; j++)
                    acc[i][j] = __builtin_amdgcn_mfma_f32_16x16x32_bf16(af[i], bfm[j], acc[i][j], 0,0,0);
        }
        __syncthreads();
    }
    #pragma unroll
    for (int i = 0; i < 4; i++)
        #pragma unroll
        for (int j = 0; j < 4; j++) {
            int n = bn + wc + j*16 + fr;
            int mbase = bm + wr + i*16 + fg*4;
            if (n < DIN) {
                #pragma unroll
                for (int ii = 0; ii < 4; ii++)
                    Xs[(size_t)(mbase+ii)*DIN + n] = f2bf(acc[i][j][ii]);
            } else {
                #pragma unroll
                for (int ii = 0; ii < 4; ii++)
                    Zb[(size_t)(mbase+ii)*DIN + (n - DIN)] = f2bf(acc[i][j][ii]);
            }
        }
}

// ===== x_proj GEMM with fused causal conv+SiLU: xs -> (xu global, x_dbl) =========
// 72 blocks, each 64 rows. Per K-chunk (64 channels): stage xs rows R0-3..R0+63,
// compute xu tile in LDS (conv k=4 + SiLU), write xu, MFMA vs wxp -> x_dbl.
__global__ __launch_bounds__(256) void xproj_conv_kernel(
    const ushort_t* __restrict__ xs, const ushort_t* __restrict__ wxp,
    const float* __restrict__ cw, const float* __restrict__ cb,
    ushort_t* __restrict__ xu, float* __restrict__ xdbl) {
    __shared__ ushort_t Xt[67][72];
    __shared__ ushort_t As[64][72];
    __shared__ ushort_t Bs[64][72];
    int tid = threadIdx.x;
    int R0 = blockIdx.x * 64;
    int lmin = (R0 >= LL) ? LL : 0;      // batch start (zero-pad before it)
    int w = tid >> 6, l = tid & 63;
    int wr = (w >> 1) * 32, wc = (w & 1) * 32;
    int fr = l & 15, fg = l >> 4;
    f32x4 acc[2][2] = {};
    for (int k0 = 0; k0 < DIN; k0 += 64) {
        // stage Xt (67 rows x 64 cols bf16, 8 uint4 per row)
        for (int i = tid; i < 67*8; i += 256) {
            int r = i >> 3, c8 = (i & 7) * 8;
            int m = R0 - 3 + r;
            uint4 v = make_uint4(0u,0u,0u,0u);
            if (m >= lmin) v = *(const uint4*)(xs + (size_t)m*DIN + k0 + c8);
            *(uint4*)&Xt[r][c8] = v;
        }
        // stage Bs (48 valid rows of wxp)
        for (int i = tid; i < 64*8; i += 256) {
            int r = i >> 3, c8 = (i & 7) * 8;
            uint4 v = make_uint4(0u,0u,0u,0u);
            if (r < 48) v = *(const uint4*)(wxp + (size_t)r*DIN + k0 + c8);
            *(uint4*)&Bs[r][c8] = v;
        }
        __syncthreads();
        // conv+silu: 64x64 tile, each thread 2 x 8 consecutive channels
        #pragma unroll
        for (int rr = 0; rr < 2; rr++) {
            int r = (tid >> 3) + rr*32;
            int c0 = (tid & 7) * 8;
            ushort_t ov[8];
            #pragma unroll
            for (int cc = 0; cc < 8; cc++) {
                int c = c0 + cc;
                float4 cwv = ((const float4*)cw)[k0 + c];
                float a = cb[k0 + c];
                a = fmaf(cwv.x, bf2f(Xt[r+0][c]), a);
                a = fmaf(cwv.y, bf2f(Xt[r+1][c]), a);
                a = fmaf(cwv.z, bf2f(Xt[r+2][c]), a);
                a = fmaf(cwv.w, bf2f(Xt[r+3][c]), a);
                ov[cc] = f2bf(silu_f(a));
            }
            *(uint4*)&As[r][c0] = *(uint4*)ov;
            *(uint4*)(xu + (size_t)(R0 + r)*DIN + k0 + c0) = *(uint4*)ov;
        }
        __syncthreads();
        #pragma unroll
        for (int kk = 0; kk < 2; kk++) {
            int ko = kk*32 + fg*8;
            bf16x8 a0 = *(const bf16x8*)&As[wr + fr][ko];
            bf16x8 a1 = *(const bf16x8*)&As[wr + 16 + fr][ko];
            bf16x8 b0 = *(const bf16x8*)&Bs[wc + fr][ko];
            bf16x8 b1 = *(const bf16x8*)&Bs[wc + 16 + fr][ko];
            acc[0][0] = __builtin_amdgcn_mfma_f32_16x16x32_bf16(a0, b0, acc[0][0], 0,0,0);
            acc[0][1] = __builtin_amdgcn_mfma_f32_16x16x32_bf16(a0, b1, acc[0][1], 0,0,0);
            acc[1][0] = __builtin_amdgcn_mfma_f32_16x16x32_bf16(a1, b0, acc[1][0], 0,0,0);
            acc[1][1] = __builtin_amdgcn_mfma_f32_16x16x32_bf16(a1, b1, acc[1][1], 0,0,0);
        }
        __syncthreads();
    }
    #pragma unroll
    for (int mi = 0; mi < 2; mi++)
        #pragma unroll
        for (int nj = 0; nj < 2; nj++) {
            int n = wc + nj*16 + fr;
            if (n < 48) {
                int mbase = R0 + wr + mi*16 + fg*4;
                #pragma unroll
                for (int i = 0; i < 4; i++)
                    xdbl[(size_t)(mbase + i)*48 + n] = acc[mi][nj][i];
            }
        }
}

// ---------------- 64x64 MFMA GEMM (out_proj EPI2: residual + transpose) -----------
template<int EPI>
__global__ __launch_bounds__(256) void mfma_gemm(const ushort_t* __restrict__ A,
    const ushort_t* __restrict__ W, float* __restrict__ C, int M, int N, int K,
    const float* __restrict__ Xres, const float* __restrict__ gammap,
    float* __restrict__ Out) {
    __shared__ ushort_t Asl[64][72];
    __shared__ ushort_t Bsl[64][72];
    int tid = threadIdx.x;
    int bm = blockIdx.y * 64;
    int bn = blockIdx.x * 64;
    int w = tid >> 6, l = tid & 63;
    int wr = (w >> 1) * 32, wc = (w & 1) * 32;
    int fr = l & 15, fg = l >> 4;
    f32x4 acc[2][2] = {};
    for (int k0 = 0; k0 < K; k0 += 64) {
        #pragma unroll
        for (int s = 0; s < 2; s++) {
            int c = tid + s*256;
            int r = c >> 3, c8 = (c & 7) * 8;
            *(uint4*)&Asl[r][c8] = *(const uint4*)(A + (size_t)(bm + r)*K + k0 + c8);
            uint4 wv = make_uint4(0u,0u,0u,0u);
            if (bn + r < N) wv = *(const uint4*)(W + (size_t)(bn + r)*K + k0 + c8);
            *(uint4*)&Bsl[r][c8] = wv;
        }
        __syncthreads();
        #pragma unroll
        for (int kk = 0; kk < 2; kk++) {
            int ko = kk*32 + fg*8;
            bf16x8 a0 = *(const bf16x8*)&Asl[wr + fr][ko];
            bf16x8 a1 = *(const bf16x8*)&Asl[wr + 16 + fr][ko];
            bf16x8 b0 = *(const bf16x8*)&Bsl[wc + fr][ko];
            bf16x8 b1 = *(const bf16x8*)&Bsl[wc + 16 + fr][ko];
            acc[0][0] = __builtin_amdgcn_mfma_f32_16x16x32_bf16(a0, b0, acc[0][0], 0,0,0);
            acc[0][1] = __builtin_amdgcn_mfma_f32_16x16x32_bf16(a0, b1, acc[0][1], 0,0,0);
            acc[1][0] = __builtin_amdgcn_mfma_f32_16x16x32_bf16(a1, b0, acc[1][0], 0,0,0);
            acc[1][1] = __builtin_amdgcn_mfma_f32_16x16x32_bf16(a1, b1, acc[1][1], 0,0,0);
        }
        __syncthreads();
    }
    if (EPI == 0) {
        #pragma unroll
        for (int mi = 0; mi < 2; mi++)
            #pragma unroll
            for (int nj = 0; nj < 2; nj++) {
                int n = bn + wc + nj*16 + fr;
                if (n < N) {
                    int mbase = bm + wr + mi*16 + fg*4;
                    #pragma unroll
                    for (int i = 0; i < 4; i++)
                        C[(size_t)(mbase + i)*N + n] = acc[mi][nj][i];
                }
            }
    } else {
        float g = gammap[0];
        int b = (bm >= LL) ? 1 : 0;
        #pragma unroll
        for (int mi = 0; mi < 2; mi++)
            #pragma unroll
            for (int nj = 0; nj < 2; nj++) {
                int n = bn + wc + nj*16 + fr;
                int mbase = bm + wr + mi*16 + fg*4;
                #pragma unroll
                for (int i = 0; i < 4; i++) {
                    size_t o = ((size_t)(b*DIMC + n))*LL + (size_t)(mbase + i - b*LL);
                    Out[o] = fmaf(g, acc[mi][nj][i], Xres[o]);
                }
            }
    }
}

// ================= chunked selective scan, thread-per-(chunk, b, d) ================
#define LOAD16(arr, p) { float4 q0=(p)[0],q1=(p)[1],q2=(p)[2],q3=(p)[3]; \
    arr[0]=q0.x;arr[1]=q0.y;arr[2]=q0.z;arr[3]=q0.w; arr[4]=q1.x;arr[5]=q1.y;arr[6]=q1.z;arr[7]=q1.w; \
    arr[8]=q2.x;arr[9]=q2.y;arr[10]=q2.z;arr[11]=q2.w; arr[12]=q3.x;arr[13]=q3.y;arr[14]=q3.z;arr[15]=q3.w; }

#define DT_DOT(dlt, xr) { float4 t0 = (xr)[0], t1 = (xr)[1], t2 = (xr)[2], t3 = (xr)[3]; \
    dlt=fmaf(t0.x,dw[0],dlt); dlt=fmaf(t0.y,dw[1],dlt); dlt=fmaf(t0.z,dw[2],dlt); dlt=fmaf(t0.w,dw[3],dlt); \
    dlt=fmaf(t1.x,dw[4],dlt); dlt=fmaf(t1.y,dw[5],dlt); dlt=fmaf(t1.z,dw[6],dlt); dlt=fmaf(t1.w,dw[7],dlt); \
    dlt=fmaf(t2.x,dw[8],dlt); dlt=fmaf(t2.y,dw[9],dlt); dlt=fmaf(t2.z,dw[10],dlt); dlt=fmaf(t2.w,dw[11],dlt); \
    dlt=fmaf(t3.x,dw[12],dlt); dlt=fmaf(t3.y,dw[13],dlt); dlt=fmaf(t3.z,dw[14],dlt); dlt=fmaf(t3.w,dw[15],dlt); }

__global__ __launch_bounds__(256) void scan_phase1(
    const ushort_t* __restrict__ xu, const float* __restrict__ xdbl,
    const float* __restrict__ dtw, const float* __restrict__ dtb,
    const float* __restrict__ A2,
    float* __restrict__ aprod, float* __restrict__ hend) {
    __shared__ float xs_s[CH*48];
    int t = blockIdx.x * 256 + threadIdx.x;
    int g = t & (NGRP-1);
    int c = t >> 10;
    int b = g >> 9, d = g & (DIN-1);
    int m0 = b*LL + c*CH;
    for (int i = threadIdx.x; i < CH*48; i += 256) xs_s[i] = xdbl[(size_t)m0*48 + i];
    float dw[16], A[16], h[16], a[16];
    LOAD16(dw, (const float4*)(dtw + (size_t)d*16));
    LOAD16(A,  (const float4*)(A2  + (size_t)d*16));
    #pragma unroll
    for (int n = 0; n < 16; n++) { h[n] = 0.f; a[n] = 1.f; }
    float bias = dtb[d];
    __syncthreads();
    for (int l = 0; l < CH; l++) {
        const float4* xr = (const float4*)&xs_s[l*48];
        float dlt = bias;
        DT_DOT(dlt, xr);
        dlt = softplus_f(dlt);
        float xv = bf2f(xu[(size_t)(m0 + l)*DIN + d]);
        float dbx = dlt * xv;
        float Bv[16];
        LOAD16(Bv, xr + 4);
        #pragma unroll
        for (int n = 0; n < 16; n++) {
            float dA = __expf(dlt * A[n]);
            h[n] = fmaf(dA, h[n], dbx * Bv[n]);
            a[n] *= dA;
        }
    }
    float4* ap = (float4*)(aprod + ((size_t)c*NGRP + g)*16);
    float4* hp = (float4*)(hend  + ((size_t)c*NGRP + g)*16);
    ap[0] = make_float4(a[0],a[1],a[2],a[3]);   ap[1] = make_float4(a[4],a[5],a[6],a[7]);
    ap[2] = make_float4(a[8],a[9],a[10],a[11]); ap[3] = make_float4(a[12],a[13],a[14],a[15]);
    hp[0] = make_float4(h[0],h[1],h[2],h[3]);   hp[1] = make_float4(h[4],h[5],h[6],h[7]);
    hp[2] = make_float4(h[8],h[9],h[10],h[11]); hp[3] = make_float4(h[12],h[13],h[14],h[15]);
}

__global__ __launch_bounds__(256) void scan_phase2(const float* __restrict__ aprod,
    const float* __restrict__ hend, float* __restrict__ hin) {
    int u = blockIdx.x * 256 + threadIdx.x;   // 0..NSEQ-1
    float h = 0.f;
    #pragma unroll 4
    for (int c = 0; c < NC; c++) {
        size_t ci = (size_t)c*NSEQ + u;
        hin[ci] = h;
        h = fmaf(aprod[ci], h, hend[ci]);
    }
}

__global__ __launch_bounds__(256) void scan_phase3(
    const ushort_t* __restrict__ xu, const float* __restrict__ xdbl,
    const float* __restrict__ dtw, const float* __restrict__ dtb,
    const float* __restrict__ A2, const float* __restrict__ Dp,
    const ushort_t* __restrict__ zb, const float* __restrict__ hin,
    ushort_t* __restrict__ yg) {
    __shared__ float xs_s[CH*48];
    int t = blockIdx.x * 256 + threadIdx.x;
    int g = t & (NGRP-1);
    int c = t >> 10;
    int b = g >> 9, d = g & (DIN-1);
    int m0 = b*LL + c*CH;
    for (int i = threadIdx.x; i < CH*48; i += 256) xs_s[i] = xdbl[(size_t)m0*48 + i];
    float dw[16], A[16], h[16];
    LOAD16(dw, (const float4*)(dtw + (size_t)d*16));
    LOAD16(A,  (const float4*)(A2  + (size_t)d*16));
    LOAD16(h,  (const float4*)(hin + ((size_t)c*NGRP + g)*16));
    float bias = dtb[d];
    float Dd = Dp[d];
    __syncthreads();
    for (int l = 0; l < CH; l++) {
        int m = m0 + l;
        const float4* xr = (const float4*)&xs_s[l*48];
        float dlt = bias;
        DT_DOT(dlt, xr);
        dlt = softplus_f(dlt);
        float xv = bf2f(xu[(size_t)m*DIN + d]);
        float dbx = dlt * xv;
        float Bv[16], Cv[16];
        LOAD16(Bv, xr + 4);
        LOAD16(Cv, xr + 8);
        float y = 0.f;
        #pragma unroll
        for (int n = 0; n < 16; n++) {
            float dA = __expf(dlt * A[n]);
            h[n] = fmaf(dA, h[n], dbx * Bv[n]);
            y = fmaf(h[n], Cv[n], y);
        }
        float z = bf2f(zb[(size_t)m*DIN + d]);
        float yv = fmaf(xv, Dd, y);
        yg[(size_t)m*DIN + d] = f2bf(yv * (z / (1.f + __expf(-z))));
    }
}

extern "C" void kernel_launch(void* const* d_in, const int* in_sizes, int n_in,
                              void* d_out, int out_size, void* d_ws, size_t ws_size,
                              hipStream_t stream) {
    const float* x         = (const float*)d_in[0];
    const float* ln_w      = (const float*)d_in[1];
    const float* ln_b      = (const float*)d_in[2];
    const float* in_proj_w = (const float*)d_in[3];
    const float* conv_w    = (const float*)d_in[4];
    const float* conv_b    = (const float*)d_in[5];
    const float* x_proj_w  = (const float*)d_in[6];
    const float* dt_proj_w = (const float*)d_in[7];
    const float* dt_proj_b = (const float*)d_in[8];
    const float* A_log     = (const float*)d_in[9];
    const float* Dp        = (const float*)d_in[10];
    const float* out_proj_w= (const float*)d_in[11];
    const float* gamma     = (const float*)d_in[12];
    float* out = (float*)d_out;

    float* ws = (float*)d_ws;
    float* x_dbl = ws;                          // MM*48 fp32
    float* aprod = x_dbl + (size_t)MM*48;       // NC*NSEQ
    float* hend  = aprod + (size_t)NC*NSEQ;     // NC*NSEQ
    float* hin   = hend  + (size_t)NC*NSEQ;     // NC*NSEQ
    float* A2    = hin   + (size_t)NC*NSEQ;     // DIN*DST
    ushort_t* xn  = (ushort_t*)(A2 + DIN*DST);  // MM*256 bf16
    ushort_t* xs  = xn  + (size_t)MM*DIMC;      // MM*512 bf16 (x half of in_proj)
    ushort_t* zb  = xs  + (size_t)MM*DIN;       // MM*512 bf16 (z half of in_proj)
    ushort_t* xu  = zb  + (size_t)MM*DIN;       // MM*512 bf16
    ushort_t* yg  = xu  + (size_t)MM*DIN;       // MM*512 bf16
    ushort_t* win = yg  + (size_t)MM*DIN;       // 1024*256 bf16
    ushort_t* wxp = win + (size_t)W0N;          // 48*512 bf16
    ushort_t* wout= wxp + (size_t)W1N;          // 256*512 bf16

    // 1. LN -> xn (bf16)  +  weights -> bf16  +  A2 = -exp(A_log)
    prep_kernel<<<NBLN + NBW, 256, 0, stream>>>(x, ln_w, ln_b, xn,
        in_proj_w, x_proj_w, out_proj_w, A_log, win, wxp, wout, A2);
    // 2. in_proj (128x128 tiles), split epilogue: xs bf16 | zb bf16
    mfma_gemm128_split<<<dim3(1024/128, MM/128), 256, 0, stream>>>(xn, win, xs, zb, DIMC);
    // 3. x_proj with fused conv+SiLU: -> xu (bf16 global) and x_dbl
    xproj_conv_kernel<<<MM/64, 256, 0, stream>>>(xs, wxp, conv_w, conv_b, xu, x_dbl);
    // 4-6. chunked selective scan (dt_proj+softplus fused; gate fused in phase3)
    scan_phase1<<<(NC*NGRP)/256, 256, 0, stream>>>(xu, x_dbl, dt_proj_w, dt_proj_b, A2, aprod, hend);
    scan_phase2<<<NSEQ/256, 256, 0, stream>>>(aprod, hend, hin);
    scan_phase3<<<(NC*NGRP)/256, 256, 0, stream>>>(xu, x_dbl, dt_proj_w, dt_proj_b, A2, Dp, zb, hin, yg);
    // 7. out_proj + residual + transpose fused
    mfma_gemm<2><<<dim3(DIMC/64, MM/64), 256, 0, stream>>>(yg, wout, nullptr, MM, DIMC, DIN, x, gamma, out);
}